// Round 22
// baseline (68.678 us; speedup 1.0000x reference)
//
#include <hip/hip_runtime.h>
#include <hip/hip_bf16.h>

// Problem constants (from reference)
#define BATCH   8
#define MROWS   2048      // C*P per batch
#define MTOT    16384     // BATCH*MROWS
#define DIM_Z   512
#define DIM_G   1024
#define EDIM    128
#define EPS     1e-6f
#define BK      64        // K-step

typedef unsigned short u16;
typedef unsigned int   u32;
typedef __attribute__((ext_vector_type(8))) short bf16x8;
typedef __attribute__((ext_vector_type(4))) float f32x4;

// f32 -> bf16 round-to-nearest-even (bit trick; inputs are finite)
__device__ __forceinline__ u16 f2b(float f) {
    u32 x = __float_as_uint(f);
    u32 r = x + 0x7fffu + ((x >> 16) & 1u);
    return (u16)(r >> 16);
}

// packed f32 pair -> 2x bf16 in one u32 (RNE), single VALU inst on gfx950
__device__ __forceinline__ u32 cvtpk(float lo, float hi) {
    u32 r;
    asm("v_cvt_pk_bf16_f32 %0, %1, %2" : "=v"(r) : "v"(lo), "v"(hi));
    return r;
}

// async global->LDS, 16B per lane, dest = wave-uniform base + lane*16
#define GLD16(gsrc, ldst) __builtin_amdgcn_global_load_lds( \
    (const __attribute__((address_space(1))) unsigned int*)(gsrc), \
    (__attribute__((address_space(3))) unsigned int*)(ldst), 16, 0, 0)

#define MEMFENCE() asm volatile("" ::: "memory")

// ---- kernel 1 (FUSED uv+wpack): W[b] = W_base + u_b (x) v_b -> bf16 + WT ----
// r21-proven. 512 blocks (16 d x 32 g), all 8 batches per block (Wbase tile in
// regs, read once). Per batch: emb row -> LDS; 64 u/v slice dots (4 lanes each,
// shfl reduce); W/WT tiles. rsum zeroing folded into first 64 blocks.
__global__ void wpack_uv(const float* __restrict__ Wbase,
                         const float* __restrict__ emb, const int* __restrict__ idx,
                         const float* __restrict__ Wu, const float* __restrict__ Wv,
                         u16* __restrict__ W, u16* __restrict__ WT,
                         float* __restrict__ rsum) {
    __shared__ float a_sh[EDIM];
    __shared__ float us[32], vs[32];
    __shared__ u16 tile[32][33];

    int h = blockIdx.x;
    int d0 = (h & 15) * 32, g0 = (h >> 4) * 32;
    int tx = threadIdx.x, ty = threadIdx.y;
    int tid = ty * 32 + tx;

    if (h < 64)   // zero rsum (runs before gemm1 in stream order)
        for (int i = tid; i < 256; i += 256) rsum[h * 256 + i] = 0.f;

    // Wbase tile -> regs (once; reused by all 8 batches)
    float base[4];
#pragma unroll
    for (int j = 0; j < 4; ++j)
        base[j] = Wbase[(size_t)(g0 + ty + j * 8) * DIM_Z + d0 + tx];

    int slot = tid >> 2, q = tid & 3;   // 64 outputs, 4 lanes each
    const float* wrow = (slot < 32) ? (Wu + (size_t)(g0 + slot) * EDIM)
                                    : (Wv + (size_t)(d0 + slot - 32) * EDIM);

    for (int b = 0; b < BATCH; ++b) {
        if (tid < EDIM) a_sh[tid] = emb[(size_t)idx[b] * EDIM + tid];
        __syncthreads();
        float s = 0.f;
#pragma unroll
        for (int i = 0; i < 32; ++i) s += a_sh[q * 32 + i] * wrow[q * 32 + i];
        s += __shfl_xor(s, 1, 64);
        s += __shfl_xor(s, 2, 64);
        if (q == 0) {
            if (slot < 32) us[slot] = s;
            else           vs[slot - 32] = s;
        }
        __syncthreads();
        float vb = vs[tx];
#pragma unroll
        for (int j = 0; j < 4; ++j) {
            int g = g0 + ty + j * 8;
            u16 h16 = f2b(base[j] + us[ty + j * 8] * vb);
            W[((size_t)b * DIM_G + g) * DIM_Z + d0 + tx] = h16;
            tile[ty + j * 8][tx] = h16;
        }
        __syncthreads();
#pragma unroll
        for (int j = 0; j < 4; ++j)
            WT[((size_t)b * DIM_Z + d0 + ty + j * 8) * DIM_G + g0 + tx] =
                tile[tx][ty + j * 8];
        __syncthreads();   // WAR on tile/a_sh before next batch
    }
}

// ---------- GEMM1 (FAT TILE + counted-vmcnt, B DOUBLE-BUFFERED lead-1) ----------
// r20 + this round's lever: Bs is double-buffered (2x32 KB) and B's issue moved
// one iteration EARLY, so B(t) — like A(t) — has a full iteration of flight
// time. Per iter t (fully unrolled, static indexing):
//   s_barrier                          [compute(t-1) reads done; NO drain]
//   issue B(t+1) gld_lds -> Bs[(t+1)&1] [its prev reader compute(t-1) done]
//   issue A(t+1) f32 -> regs
//   cvt + ds_write A(t)                [scoreboard waits A(t) only]
//   s_waitcnt vmcnt(16) lgkmcnt(0)     [newest 16 = A(t+1)+B(t+1) stay in
//                                       flight; B(t) — a full iter old — drains]
//   s_barrier -> ds_read + 32 MFMA/wave from As + Bs[t&1]
// LDS 80 KB, LB(256,2) (2 x 80 = 160 KB/CU exactly). The "memory"-clobbered
// asm waits pin issue order (r20-validated). Tail t=7: vmcnt(0).
// Tile 128m x 256n, 4 waves of 64x128. XCD decode: xcd = h&7 owns batch xcd's
// m-range. qg NORMAL store (L2-hot for gemm2 — r13 lesson).
__global__ __launch_bounds__(256, 2)
void gemm1(const float* __restrict__ qz, const u16* __restrict__ Wall,
           u16* __restrict__ qg, float* __restrict__ rsum) {
    const int N = DIM_G, K = DIM_Z;
    __shared__ u16 As[128 * BK];      // 16 KB
    __shared__ u16 Bs[2][256 * BK];   // 2 x 32 KB

    int h = blockIdx.x;
    int xcd = h & 7, idx = h >> 3;
    int tile = xcd * 64 + idx;               // 16 mT x 4 nT per XCD
    int mBase = (tile >> 2) * 128;
    int nBase = (tile & 3) * 256;
    int b = mBase >> 11;                      // == xcd

    int tid  = threadIdx.x;
    int lane = tid & 63, wid = tid >> 6;
    int wm = wid >> 1, wn = wid & 1;          // 2M x 2N fat waves
    int lr = lane & 15, lg = lane >> 4;

    f32x4 acc[4][8] = {};

    int sRow = tid >> 3;                      // 0..31
    int sC   = tid & 7;
    int cw   = sC ^ (sRow & 7);
    const float* aSrc = qz + (size_t)(mBase + sRow) * K + sC * 8;     // straight
    const u16*   bSrc = Wall + (size_t)b * DIM_G * DIM_Z
                             + (size_t)(nBase + sRow) * K + cw * 8;   // pre-swz

    float4 alo[2][4], ahi[2][4];
    // prologue: A(0) -> regs, B(0) -> Bs[0] (both get a full barrier+issue
    // phase of iter 0 to land)
#pragma unroll
    for (int r = 0; r < 4; ++r) {
        const float* g = aSrc + (size_t)r * 32 * K;
        alo[0][r] = *(const float4*)g;
        ahi[0][r] = *(const float4*)(g + 4);
    }
#pragma unroll
    for (int r = 0; r < 8; ++r)
        GLD16(bSrc + (size_t)r * 32 * K, &Bs[0][(r * 256 + wid * 64) * 8]);

#pragma unroll
    for (int t = 0; t < 8; ++t) {             // K/BK == 8, fully unrolled
        const int cur = t & 1, nxt = cur ^ 1; // compile-time after unroll
        __builtin_amdgcn_s_barrier();         // compute(t-1) reads done; no drain
        MEMFENCE();
        if (t < 7) {
#pragma unroll
            for (int r = 0; r < 8; ++r)       // issue B(t+1) -> other buffer
                GLD16(bSrc + (size_t)r * 32 * K + (t + 1) * BK,
                      &Bs[nxt][(r * 256 + wid * 64) * 8]);
#pragma unroll
            for (int r = 0; r < 4; ++r) {     // issue A(t+1) -> regs (lead-1)
                const float* g = aSrc + (size_t)r * 32 * K + (t + 1) * BK;
                alo[nxt][r] = *(const float4*)g;
                ahi[nxt][r] = *(const float4*)(g + 4);
            }
        }
#pragma unroll
        for (int r = 0; r < 4; ++r) {         // cvt + swizzled ds_write A(t)
            uint4 q;
            q.x = cvtpk(alo[cur][r].x, alo[cur][r].y);
            q.y = cvtpk(alo[cur][r].z, alo[cur][r].w);
            q.z = cvtpk(ahi[cur][r].x, ahi[cur][r].y);
            q.w = cvtpk(ahi[cur][r].z, ahi[cur][r].w);
            *(uint4*)&As[(r * 32 + sRow) * BK + cw * 8] = q;
        }
        // newest 16 = A(t+1) 8 + B(t+1) 8 stay in flight; B(t) (issued a full
        // iteration ago) + everything older drains. Tail: full drain.
        if (t < 7) asm volatile("s_waitcnt vmcnt(16) lgkmcnt(0)" ::: "memory");
        else       asm volatile("s_waitcnt vmcnt(0) lgkmcnt(0)" ::: "memory");
        __builtin_amdgcn_s_barrier();         // all waves' tile writes visible
        MEMFENCE();
#pragma unroll
        for (int ks = 0; ks < 2; ++ks) {
            bf16x8 af[4], bfr[8];
#pragma unroll
            for (int mi = 0; mi < 4; ++mi) {
                int row = wm * 64 + mi * 16 + lr;
                int cq  = (ks * 4 + lg) ^ (row & 7);
                af[mi] = *(const bf16x8*)&As[row * BK + cq * 8];
            }
#pragma unroll
            for (int ni = 0; ni < 8; ++ni) {
                int row = wn * 128 + ni * 16 + lr;
                int cq  = (ks * 4 + lg) ^ (row & 7);
                bfr[ni] = *(const bf16x8*)&Bs[cur][row * BK + cq * 8];
            }
            __builtin_amdgcn_s_setprio(1);
#pragma unroll
            for (int mi = 0; mi < 4; ++mi)
#pragma unroll
                for (int ni = 0; ni < 8; ++ni)
                    acc[mi][ni] = __builtin_amdgcn_mfma_f32_16x16x32_bf16(
                        af[mi], bfr[ni], acc[mi][ni], 0, 0, 0);
            __builtin_amdgcn_s_setprio(0);
        }
        MEMFENCE();
    }

    int mw = mBase + wm * 64, nw = nBase + wn * 128;
#pragma unroll
    for (int mi = 0; mi < 4; ++mi)
#pragma unroll
        for (int r = 0; r < 4; ++r) {
            int m = mw + mi * 16 + lg * 4 + r;
            float vals[8];
            float s = 0.f;
#pragma unroll
            for (int ni = 0; ni < 8; ++ni) {
                vals[ni] = fmaxf(acc[mi][ni][r], 0.f);
                s += vals[ni];
            }
#pragma unroll
            for (int ni = 0; ni < 8; ++ni)
                qg[(size_t)m * N + nw + ni * 16 + lr] = f2b(vals[ni]);
            s += __shfl_xor(s, 1, 64);
            s += __shfl_xor(s, 2, 64);
            s += __shfl_xor(s, 4, 64);
            s += __shfl_xor(s, 8, 64);
            if (lr == 0) atomicAdd(&rsum[m], s);
        }
}

// ---------------- GEMM2: out = (qg @ WT[b]^T) / max(rsum,eps) ----------------
// The champion ~24 µs structure (UNCHANGED): both operands via global_load_lds,
// 128x128, (256,4), per-XCD m-range matching GEMM1 (qg L2-hot), NT out store.
__global__ __launch_bounds__(256, 4)
void gemm2(const u16* __restrict__ qg, const u16* __restrict__ WTall,
           const float* __restrict__ rsum, float* __restrict__ out) {
    const int N = DIM_Z, K = DIM_G;
    __shared__ u16 As[128 * BK];   // 16 KB
    __shared__ u16 Bs[128 * BK];   // 16 KB

    int h = blockIdx.x;
    int xcd = h & 7, idx = h >> 3;
    int tile = xcd * 64 + idx;               // 16 mT x 4 nT per XCD
    int mBase = (tile >> 2) * 128;
    int nBase = (tile & 3) * 128;
    int b = mBase >> 11;                      // == xcd

    int tid  = threadIdx.x;
    int lane = tid & 63, wid = tid >> 6;
    int wm = wid >> 1, wn = wid & 1;
    int lr = lane & 15, lg = lane >> 4;

    f32x4 acc[4][4] = {};

    int sRow = tid >> 3;
    int cw   = (tid & 7) ^ (sRow & 7);
    const u16* aSrc = qg + (size_t)(mBase + sRow) * K + cw * 8;
    const u16* bSrc = WTall + (size_t)b * DIM_Z * DIM_G
                            + (size_t)(nBase + sRow) * K + cw * 8;

    for (int kt = 0; kt < K; kt += BK) {
        __syncthreads();
#pragma unroll
        for (int r = 0; r < 4; ++r) {
            GLD16(aSrc + (size_t)r * 32 * K + kt, &As[(r * 256 + wid * 64) * 8]);
            GLD16(bSrc + (size_t)r * 32 * K + kt, &Bs[(r * 256 + wid * 64) * 8]);
        }
        __syncthreads();
#pragma unroll
        for (int ks = 0; ks < 2; ++ks) {
            bf16x8 af[4], bfr[4];
#pragma unroll
            for (int mi = 0; mi < 4; ++mi) {
                int row = wm * 64 + mi * 16 + lr;
                int cq  = (ks * 4 + lg) ^ (row & 7);
                af[mi] = *(const bf16x8*)&As[row * BK + cq * 8];
            }
#pragma unroll
            for (int ni = 0; ni < 4; ++ni) {
                int row = wn * 64 + ni * 16 + lr;
                int cq  = (ks * 4 + lg) ^ (row & 7);
                bfr[ni] = *(const bf16x8*)&Bs[row * BK + cq * 8];
            }
            __builtin_amdgcn_s_setprio(1);
#pragma unroll
            for (int mi = 0; mi < 4; ++mi)
#pragma unroll
                for (int ni = 0; ni < 4; ++ni)
                    acc[mi][ni] = __builtin_amdgcn_mfma_f32_16x16x32_bf16(
                        af[mi], bfr[ni], acc[mi][ni], 0, 0, 0);
            __builtin_amdgcn_s_setprio(0);
        }
    }

    int mw = mBase + wm * 64, nw = nBase + wn * 64;
#pragma unroll
    for (int mi = 0; mi < 4; ++mi)
#pragma unroll
        for (int r = 0; r < 4; ++r) {
            int m = mw + mi * 16 + lg * 4 + r;
            float inv = 1.f / fmaxf(rsum[m], EPS);
#pragma unroll
            for (int ni = 0; ni < 4; ++ni)
                __builtin_nontemporal_store(acc[mi][ni][r] * inv,
                    &out[(size_t)m * N + nw + ni * 16 + lr]);
        }
}

extern "C" void kernel_launch(void* const* d_in, const int* in_sizes, int n_in,
                              void* d_out, int out_size, void* d_ws, size_t ws_size,
                              hipStream_t stream) {
    const float* qz    = (const float*)d_in[0];
    const int*   attr  = (const int*)d_in[1];
    const float* Wbase = (const float*)d_in[2];
    const float* emb   = (const float*)d_in[3];
    const float* Wu    = (const float*)d_in[4];
    const float* Wv    = (const float*)d_in[5];
    float* out = (float*)d_out;

    // workspace carve-up (all 256B aligned)
    char* ws = (char*)d_ws;
    size_t off = 0;
    auto alloc = [&](size_t bytes) -> void* {
        void* p = ws + off;
        off = (off + bytes + 255) & ~(size_t)255;
        return p;
    };
    float* rsum = (float*)alloc((size_t)MTOT * 4);
    u16*   W    = (u16*)  alloc((size_t)BATCH * DIM_G * DIM_Z * 2);
    u16*   WT   = (u16*)  alloc((size_t)BATCH * DIM_G * DIM_Z * 2);
    u16*   qg   = (u16*)  alloc((size_t)MTOT * DIM_G * 2);
    if (off > ws_size) return;  // fail loudly (zero output) rather than corrupt

    // fused uv+wpack: 512 blocks (16 d x 32 g), all batches per block
    wpack_uv<<<dim3(512), dim3(32, 8), 0, stream>>>(
        Wbase, emb, attr, Wu, Wv, W, WT, rsum);

    // GEMM1 (fat 128x256, counted-vmcnt, B-dbuf lead-1): 512 blocks
    gemm1<<<dim3(512), dim3(256), 0, stream>>>(qz, W, qg, rsum);

    // GEMM2 (champion 128x128): 16 mT x 4 nT x 8 xcd = 512 blocks
    gemm2<<<dim3(512), dim3(256), 0, stream>>>(qg, WT, rsum, out);
}

// Round 23
// 68.155 us; speedup vs baseline: 1.0077x; 1.0077x over previous
//
#include <hip/hip_runtime.h>
#include <hip/hip_bf16.h>

// Problem constants (from reference)
#define BATCH   8
#define MROWS   2048      // C*P per batch
#define MTOT    16384     // BATCH*MROWS
#define DIM_Z   512
#define DIM_G   1024
#define EDIM    128
#define EPS     1e-6f
#define BK      64        // K-step

typedef unsigned short u16;
typedef unsigned int   u32;
typedef __attribute__((ext_vector_type(8))) short bf16x8;
typedef __attribute__((ext_vector_type(4))) float f32x4;

// f32 -> bf16 round-to-nearest-even (bit trick; inputs are finite)
__device__ __forceinline__ u16 f2b(float f) {
    u32 x = __float_as_uint(f);
    u32 r = x + 0x7fffu + ((x >> 16) & 1u);
    return (u16)(r >> 16);
}

// packed f32 pair -> 2x bf16 in one u32 (RNE), single VALU inst on gfx950
__device__ __forceinline__ u32 cvtpk(float lo, float hi) {
    u32 r;
    asm("v_cvt_pk_bf16_f32 %0, %1, %2" : "=v"(r) : "v"(lo), "v"(hi));
    return r;
}

// async global->LDS, 16B per lane, dest = wave-uniform base + lane*16
#define GLD16(gsrc, ldst) __builtin_amdgcn_global_load_lds( \
    (const __attribute__((address_space(1))) unsigned int*)(gsrc), \
    (__attribute__((address_space(3))) unsigned int*)(ldst), 16, 0, 0)

#define MEMFENCE() asm volatile("" ::: "memory")

// ---- kernel 1 (FUSED uv+wpack, 2 batch-groups): W[b] = W_base + u (x) v ----
// 1024 blocks: tile = h&511 (16 d x 32 g), group = h>>9 handles batches
// 4*group..4*group+3 (halves the serial batch chain vs r21). Wbase tile in
// regs (read once per block). rsum zeroing folded into blocks h<64.
__global__ void wpack_uv(const float* __restrict__ Wbase,
                         const float* __restrict__ emb, const int* __restrict__ idx,
                         const float* __restrict__ Wu, const float* __restrict__ Wv,
                         u16* __restrict__ W, u16* __restrict__ WT,
                         float* __restrict__ rsum) {
    __shared__ float a_sh[EDIM];
    __shared__ float us[32], vs[32];
    __shared__ u16 tile[32][33];

    int h = blockIdx.x;
    int t9 = h & 511, grp = h >> 9;
    int d0 = (t9 & 15) * 32, g0 = (t9 >> 4) * 32;
    int tx = threadIdx.x, ty = threadIdx.y;
    int tid = ty * 32 + tx;

    if (h < 64)   // zero rsum (runs before gemm1 in stream order)
        for (int i = tid; i < 256; i += 256) rsum[h * 256 + i] = 0.f;

    // Wbase tile -> regs (once; reused by this block's 4 batches)
    float base[4];
#pragma unroll
    for (int j = 0; j < 4; ++j)
        base[j] = Wbase[(size_t)(g0 + ty + j * 8) * DIM_Z + d0 + tx];

    int slot = tid >> 2, q = tid & 3;   // 64 outputs, 4 lanes each
    const float* wrow = (slot < 32) ? (Wu + (size_t)(g0 + slot) * EDIM)
                                    : (Wv + (size_t)(d0 + slot - 32) * EDIM);

    for (int bb = 0; bb < 4; ++bb) {
        int b = grp * 4 + bb;
        if (tid < EDIM) a_sh[tid] = emb[(size_t)idx[b] * EDIM + tid];
        __syncthreads();
        float s = 0.f;
#pragma unroll
        for (int i = 0; i < 32; ++i) s += a_sh[q * 32 + i] * wrow[q * 32 + i];
        s += __shfl_xor(s, 1, 64);
        s += __shfl_xor(s, 2, 64);
        if (q == 0) {
            if (slot < 32) us[slot] = s;
            else           vs[slot - 32] = s;
        }
        __syncthreads();
        float vb = vs[tx];
#pragma unroll
        for (int j = 0; j < 4; ++j) {
            int g = g0 + ty + j * 8;
            u16 h16 = f2b(base[j] + us[ty + j * 8] * vb);
            W[((size_t)b * DIM_G + g) * DIM_Z + d0 + tx] = h16;
            tile[ty + j * 8][tx] = h16;
        }
        __syncthreads();
#pragma unroll
        for (int j = 0; j < 4; ++j)
            WT[((size_t)b * DIM_Z + d0 + ty + j * 8) * DIM_G + g0 + tx] =
                tile[tx][ty + j * 8];
        __syncthreads();   // WAR on tile/a_sh before next batch
    }
}

// ---------- GEMM1 (FAT TILE + counted-vmcnt) — r21 champion, UNCHANGED ----------
// Per iter t: s_barrier (no drain) -> issue B(t) gld_lds (8) -> issue A(t+1)
// f32->regs (8) -> cvt+ds_write A(t) -> vmcnt(8) lgkmcnt(0) [A(t+1) stays in
// flight across the barrier] -> s_barrier -> ds_read + 32 MFMA/wave.
// Tile 128m x 256n, 4 waves of 64x128, BK=64, LDS 48 KB, LB(256,2).
// XCD decode: xcd = h&7 owns batch xcd's m-range. qg NORMAL store (L2-hot).
__global__ __launch_bounds__(256, 2)
void gemm1(const float* __restrict__ qz, const u16* __restrict__ Wall,
           u16* __restrict__ qg, float* __restrict__ rsum) {
    const int N = DIM_G, K = DIM_Z;
    __shared__ u16 As[128 * BK];   // 16 KB
    __shared__ u16 Bs[256 * BK];   // 32 KB

    int h = blockIdx.x;
    int xcd = h & 7, idx = h >> 3;
    int tile = xcd * 64 + idx;               // 16 mT x 4 nT per XCD
    int mBase = (tile >> 2) * 128;
    int nBase = (tile & 3) * 256;
    int b = mBase >> 11;                      // == xcd

    int tid  = threadIdx.x;
    int lane = tid & 63, wid = tid >> 6;
    int wm = wid >> 1, wn = wid & 1;          // 2M x 2N fat waves
    int lr = lane & 15, lg = lane >> 4;

    f32x4 acc[4][8] = {};

    int sRow = tid >> 3;                      // 0..31
    int sC   = tid & 7;
    int cw   = sC ^ (sRow & 7);
    const float* aSrc = qz + (size_t)(mBase + sRow) * K + sC * 8;     // straight
    const u16*   bSrc = Wall + (size_t)b * DIM_G * DIM_Z
                             + (size_t)(nBase + sRow) * K + cw * 8;   // pre-swz

    float4 alo[2][4], ahi[2][4];
    // prologue: issue A(0) loads (land under iter-0's B-issue + barrier)
#pragma unroll
    for (int r = 0; r < 4; ++r) {
        const float* g = aSrc + (size_t)r * 32 * K;
        alo[0][r] = *(const float4*)g;
        ahi[0][r] = *(const float4*)(g + 4);
    }

#pragma unroll
    for (int t = 0; t < 8; ++t) {             // K/BK == 8, fully unrolled
        const int cur = t & 1, nxt = cur ^ 1; // compile-time after unroll
        __builtin_amdgcn_s_barrier();         // compute(t-1) reads done; no drain
        MEMFENCE();
#pragma unroll
        for (int r = 0; r < 8; ++r)           // issue B(t): 256 rows
            GLD16(bSrc + (size_t)r * 32 * K + t * BK, &Bs[(r * 256 + wid * 64) * 8]);
        if (t < 7) {                          // issue A(t+1) -> regs (lead-1)
#pragma unroll
            for (int r = 0; r < 4; ++r) {
                const float* g = aSrc + (size_t)r * 32 * K + (t + 1) * BK;
                alo[nxt][r] = *(const float4*)g;
                ahi[nxt][r] = *(const float4*)(g + 4);
            }
        }
#pragma unroll
        for (int r = 0; r < 4; ++r) {         // cvt + swizzled ds_write A(t)
            uint4 q;
            q.x = cvtpk(alo[cur][r].x, alo[cur][r].y);
            q.y = cvtpk(alo[cur][r].z, alo[cur][r].w);
            q.z = cvtpk(ahi[cur][r].x, ahi[cur][r].y);
            q.w = cvtpk(ahi[cur][r].z, ahi[cur][r].w);
            *(uint4*)&As[(r * 32 + sRow) * BK + cw * 8] = q;
        }
        // B(t) landed + ds_writes done; A(t+1) (newest 8) stays in flight
        if (t < 7) asm volatile("s_waitcnt vmcnt(8) lgkmcnt(0)" ::: "memory");
        else       asm volatile("s_waitcnt vmcnt(0) lgkmcnt(0)" ::: "memory");
        __builtin_amdgcn_s_barrier();         // all waves' tile writes visible
        MEMFENCE();
#pragma unroll
        for (int ks = 0; ks < 2; ++ks) {
            bf16x8 af[4], bfr[8];
#pragma unroll
            for (int mi = 0; mi < 4; ++mi) {
                int row = wm * 64 + mi * 16 + lr;
                int cq  = (ks * 4 + lg) ^ (row & 7);
                af[mi] = *(const bf16x8*)&As[row * BK + cq * 8];
            }
#pragma unroll
            for (int ni = 0; ni < 8; ++ni) {
                int row = wn * 128 + ni * 16 + lr;
                int cq  = (ks * 4 + lg) ^ (row & 7);
                bfr[ni] = *(const bf16x8*)&Bs[row * BK + cq * 8];
            }
            __builtin_amdgcn_s_setprio(1);
#pragma unroll
            for (int mi = 0; mi < 4; ++mi)
#pragma unroll
                for (int ni = 0; ni < 8; ++ni)
                    acc[mi][ni] = __builtin_amdgcn_mfma_f32_16x16x32_bf16(
                        af[mi], bfr[ni], acc[mi][ni], 0, 0, 0);
            __builtin_amdgcn_s_setprio(0);
        }
        MEMFENCE();
    }

    int mw = mBase + wm * 64, nw = nBase + wn * 128;
#pragma unroll
    for (int mi = 0; mi < 4; ++mi)
#pragma unroll
        for (int r = 0; r < 4; ++r) {
            int m = mw + mi * 16 + lg * 4 + r;
            float vals[8];
            float s = 0.f;
#pragma unroll
            for (int ni = 0; ni < 8; ++ni) {
                vals[ni] = fmaxf(acc[mi][ni][r], 0.f);
                s += vals[ni];
            }
#pragma unroll
            for (int ni = 0; ni < 8; ++ni)
                qg[(size_t)m * N + nw + ni * 16 + lr] = f2b(vals[ni]);
            s += __shfl_xor(s, 1, 64);
            s += __shfl_xor(s, 2, 64);
            s += __shfl_xor(s, 4, 64);
            s += __shfl_xor(s, 8, 64);
            if (lr == 0) atomicAdd(&rsum[m], s);
        }
}

// ---- GEMM2 (counted-vmcnt lead-1 dbuf — r20's winning recipe applied here) ----
// out = (qg @ WT[b]^T) / max(rsum,eps). Both operands dbuf'd (64 KB LDS; grid
// 512 = 2 blocks/CU so no occupancy loss). Per iter t (16 iters, unrolled):
//   s_barrier (no drain) -> issue A(t+1)+B(t+1) gld_lds into other buffers
//   -> vmcnt(8) [t's 8 loads, issued a full iter ago, drain free; t+1's fly]
//   -> s_barrier -> ds_read + MFMA from buf[t&1].
// Buffer lifetime: buf[(t+1)&1]'s last reader compute(t-1) finished at this
// iter's top barrier. Tail t=15: vmcnt(0). NT out store.
__global__ __launch_bounds__(256, 2)
void gemm2(const u16* __restrict__ qg, const u16* __restrict__ WTall,
           const float* __restrict__ rsum, float* __restrict__ out) {
    const int N = DIM_Z, K = DIM_G;
    __shared__ u16 As[2][128 * BK];   // 2 x 16 KB
    __shared__ u16 Bs[2][128 * BK];   // 2 x 16 KB

    int h = blockIdx.x;
    int xcd = h & 7, idx = h >> 3;
    int tile = xcd * 64 + idx;               // 16 mT x 4 nT per XCD
    int mBase = (tile >> 2) * 128;
    int nBase = (tile & 3) * 128;
    int b = mBase >> 11;                      // == xcd

    int tid  = threadIdx.x;
    int lane = tid & 63, wid = tid >> 6;
    int wm = wid >> 1, wn = wid & 1;
    int lr = lane & 15, lg = lane >> 4;

    f32x4 acc[4][4] = {};

    int sRow = tid >> 3;
    int cw   = (tid & 7) ^ (sRow & 7);
    const u16* aSrc = qg + (size_t)(mBase + sRow) * K + cw * 8;
    const u16* bSrc = WTall + (size_t)b * DIM_Z * DIM_G
                            + (size_t)(nBase + sRow) * K + cw * 8;

    // prologue: tile 0 -> buf 0 (lands under iter 0's issue phase + barrier)
#pragma unroll
    for (int r = 0; r < 4; ++r) {
        GLD16(aSrc + (size_t)r * 32 * K, &As[0][(r * 256 + wid * 64) * 8]);
        GLD16(bSrc + (size_t)r * 32 * K, &Bs[0][(r * 256 + wid * 64) * 8]);
    }

#pragma unroll
    for (int t = 0; t < 16; ++t) {            // K/BK == 16, fully unrolled
        const int cur = t & 1, nxt = cur ^ 1;
        __builtin_amdgcn_s_barrier();         // compute(t-1) reads done; no drain
        MEMFENCE();
        if (t < 15) {
#pragma unroll
            for (int r = 0; r < 4; ++r) {     // issue tile t+1 -> other buffers
                GLD16(aSrc + (size_t)r * 32 * K + (t + 1) * BK,
                      &As[nxt][(r * 256 + wid * 64) * 8]);
                GLD16(bSrc + (size_t)r * 32 * K + (t + 1) * BK,
                      &Bs[nxt][(r * 256 + wid * 64) * 8]);
            }
            asm volatile("s_waitcnt vmcnt(8)" ::: "memory");  // t's loads done
        } else {
            asm volatile("s_waitcnt vmcnt(0)" ::: "memory");  // tail drain
        }
        __builtin_amdgcn_s_barrier();         // all waves' tile-t writes visible
        MEMFENCE();
#pragma unroll
        for (int ks = 0; ks < 2; ++ks) {
            bf16x8 af[4], bfr[4];
#pragma unroll
            for (int mi = 0; mi < 4; ++mi) {
                int row = wm * 64 + mi * 16 + lr;
                int cq  = (ks * 4 + lg) ^ (row & 7);
                af[mi] = *(const bf16x8*)&As[cur][row * BK + cq * 8];
            }
#pragma unroll
            for (int ni = 0; ni < 4; ++ni) {
                int row = wn * 64 + ni * 16 + lr;
                int cq  = (ks * 4 + lg) ^ (row & 7);
                bfr[ni] = *(const bf16x8*)&Bs[cur][row * BK + cq * 8];
            }
            __builtin_amdgcn_s_setprio(1);
#pragma unroll
            for (int mi = 0; mi < 4; ++mi)
#pragma unroll
                for (int ni = 0; ni < 4; ++ni)
                    acc[mi][ni] = __builtin_amdgcn_mfma_f32_16x16x32_bf16(
                        af[mi], bfr[ni], acc[mi][ni], 0, 0, 0);
            __builtin_amdgcn_s_setprio(0);
        }
        MEMFENCE();
    }

    int mw = mBase + wm * 64, nw = nBase + wn * 64;
#pragma unroll
    for (int mi = 0; mi < 4; ++mi)
#pragma unroll
        for (int r = 0; r < 4; ++r) {
            int m = mw + mi * 16 + lg * 4 + r;
            float inv = 1.f / fmaxf(rsum[m], EPS);
#pragma unroll
            for (int ni = 0; ni < 4; ++ni)
                __builtin_nontemporal_store(acc[mi][ni][r] * inv,
                    &out[(size_t)m * N + nw + ni * 16 + lr]);
        }
}

extern "C" void kernel_launch(void* const* d_in, const int* in_sizes, int n_in,
                              void* d_out, int out_size, void* d_ws, size_t ws_size,
                              hipStream_t stream) {
    const float* qz    = (const float*)d_in[0];
    const int*   attr  = (const int*)d_in[1];
    const float* Wbase = (const float*)d_in[2];
    const float* emb   = (const float*)d_in[3];
    const float* Wu    = (const float*)d_in[4];
    const float* Wv    = (const float*)d_in[5];
    float* out = (float*)d_out;

    // workspace carve-up (all 256B aligned)
    char* ws = (char*)d_ws;
    size_t off = 0;
    auto alloc = [&](size_t bytes) -> void* {
        void* p = ws + off;
        off = (off + bytes + 255) & ~(size_t)255;
        return p;
    };
    float* rsum = (float*)alloc((size_t)MTOT * 4);
    u16*   W    = (u16*)  alloc((size_t)BATCH * DIM_G * DIM_Z * 2);
    u16*   WT   = (u16*)  alloc((size_t)BATCH * DIM_G * DIM_Z * 2);
    u16*   qg   = (u16*)  alloc((size_t)MTOT * DIM_G * 2);
    if (off > ws_size) return;  // fail loudly (zero output) rather than corrupt

    // fused uv+wpack: 1024 blocks (512 tiles x 2 batch-groups)
    wpack_uv<<<dim3(1024), dim3(32, 8), 0, stream>>>(
        Wbase, emb, attr, Wu, Wv, W, WT, rsum);

    // GEMM1 (fat 128x256, counted-vmcnt — r21 champion): 512 blocks
    gemm1<<<dim3(512), dim3(256), 0, stream>>>(qz, W, qg, rsum);

    // GEMM2 (counted-vmcnt lead-1 dbuf): 512 blocks
    gemm2<<<dim3(512), dim3(256), 0, stream>>>(qg, WT, rsum, out);
}